// Round 20
// baseline (1932.783 us; speedup 1.0000x reference)
//
#include <hip/hip_runtime.h>

typedef unsigned short u16;
typedef __attribute__((ext_vector_type(4))) unsigned short u16x4;
typedef __attribute__((ext_vector_type(8))) short bf16x8;
typedef __attribute__((ext_vector_type(4))) float f32x4;

#define BB 128
#define SS 256
#define LWW 20
#define NTg 10
#define HWg 200
#define G4 800
#define DWg 300
#define DIN 350
#define KP 352
#define NP 896
#define NW (BB*SS)
#define OUTN (NW*NTg)

__device__ __forceinline__ float b2f(u16 u){ return __uint_as_float(((unsigned)u)<<16); }
__device__ __forceinline__ u16 f2b(float f){
  unsigned x = __float_as_uint(f);
  unsigned r = (x + 0x7fffu + ((x>>16)&1u)) >> 16;
  return (u16)r;
}
__device__ __forceinline__ float ldf(const void* p, long long i, int isb){
  return isb ? b2f(((const u16*)p)[i]) : ((const float*)p)[i];
}
__device__ __forceinline__ int ldi(const void* p, long long i, int i64){
  return i64 ? (int)((const long long*)p)[i] : ((const int*)p)[i];
}
__device__ __forceinline__ f32x4 mfma16(bf16x8 a, bf16x8 b, f32x4 c){
  return __builtin_amdgcn_mfma_f32_16x16x32_bf16(a,b,c,0,0,0);
}
__device__ __forceinline__ float sigf(float x){
  return __builtin_amdgcn_rcpf(1.f + __expf(-x));
}
__device__ __forceinline__ float tanhf_(float x){
  return 1.f - 2.f*__builtin_amdgcn_rcpf(1.f + __expf(2.f*x));
}

// ---------------- diagnostic --------------------------------------------------
__global__ void k_diag(float* out, float code){
  int i = blockIdx.x*256 + threadIdx.x;
  if(i<OUTN) out[i]=code;
}

// ---------------- fused probes ------------------------------------------------
__global__ void k_probes(const void* p, const int* __restrict__ words,
                         int* flag, int* iflag){
  __shared__ int cnt, zc;
  if(threadIdx.x==0){ cnt=0; zc=0; }
  __syncthreads();
  float a = fabsf(b2f(((const u16*)p)[threadIdx.x]));
  if(a>1e-5f && a<1.0f) atomicAdd(&cnt,1);
  if(threadIdx.x<64){
    int z=0;
    for(int k=threadIdx.x;k<128;k+=64)
      if(words[2*k+1]==0) z++;
    atomicAdd(&zc,z);
  }
  __syncthreads();
  if(threadIdx.x==0){ *flag=(cnt>=100)?1:0; *iflag=(zc>=100)?1:0; }
}

// ---------------- mega staging kernel (range-dispatched) ----------------------
__device__ __forceinline__ void st_wih(const void* src, u16* dst, int isb, int i){
  if(i>=NP*KP) return;
  int n=i/KP, k=i-n*KP;
  float v = (n<G4 && k<DIN) ? ldf(src,(long long)n*DIN+k,isb) : 0.f;
  dst[i]=f2b(v);
}
// w_hh -> MFMA B-frags, INTERLEAVED row order n' = j*4+gate (r16 layout)
__device__ __forceinline__ void st_whh(const void* src, u16* dst, int isb, int i){
  if(i>=179200) return;
  int tile=i/3584, r=i%3584, ks=r/512, r2=r%512, l=r2/8, jreg=r2%8;
  int c = tile*16 + (l&15);
  int j = c>>2, gate = c&3;
  int n = gate*200 + j;
  int k = ks*32 + ((l>>4)<<3) + jreg;
  float v = (k<HWg)? ldf(src,(long long)n*HWg+k,isb) : 0.f;
  dst[i]=f2b(v);
}
__global__ void k_stage(const void* wihf, const void* wihb,
                        const void* whhf, const void* whhb,
                        const void* echar, const void* convw, const void* cb,
                        const void* bfp, const void* bbp, const void* pw, const void* pb,
                        u16* dWIHF, u16* dWIHB, u16* dWHHF, u16* dWHHB,
                        float* d_ec, float* d_cw, float* d_cb,
                        float* d_bf, float* d_bb, float* d_pw, float* d_pb,
                        const int* __restrict__ flag){
  int isb=*flag;
  int bx=blockIdx.x, tid=threadIdx.x;
  if(bx<1232){ st_wih(wihf,dWIHF,isb,bx*256+tid); return; }
  bx-=1232;
  if(bx<1232){ st_wih(wihb,dWIHB,isb,bx*256+tid); return; }
  bx-=1232;
  if(bx<700){ st_whh(whhf,dWHHF,isb,bx*256+tid); return; }
  bx-=700;
  if(bx<700){ st_whh(whhb,dWHHB,isb,bx*256+tid); return; }
  bx-=700;
  int i = bx*256 + tid;
  if(i<2025){ d_ec[i]=ldf(echar,i,isb); return; } i-=2025;   // 81*25
  if(i<3750){ d_cw[i]=ldf(convw,i,isb); return; } i-=3750;   // 50*3*25
  if(i<64){ d_cb[i]=(i<50)?ldf(cb,i,isb):0.f; return; } i-=64;
  if(i<800){ d_bf[i]=ldf(bfp,i,isb); return; } i-=800;
  if(i<800){ d_bb[i]=ldf(bbp,i,isb); return; } i-=800;
  if(i<4000){ d_pw[i]=ldf(pw,i,isb); return; } i-=4000;
  if(i<16){ d_pb[i]=(i<10)?ldf(pb,i,isb):0.f; return; }
}

// ---------------- fused feats: word-emb gather + char CNN --------------------
__global__ __launch_bounds__(256) void k_feats(const void* __restrict__ words,
                      const void* __restrict__ chars, const void* __restrict__ embw,
                      const float* __restrict__ ec, const float* __restrict__ cw,
                      const float* __restrict__ cb, u16* __restrict__ feats,
                      const int* __restrict__ flag, const int* __restrict__ iflag){
  int isb=*flag, i64=*iflag;
  int bx=blockIdx.x, tid=threadIdx.x;
  if(bx<8192){
    int wv=tid>>6, lane=tid&63;
    int row = bx*4 + wv;
    int idx = ldi(words,row,i64);
    u16* d = feats + (size_t)row*KP;
    if(isb){
      const u16* s=(const u16*)embw + (long long)idx*DWg;
      for(int c=lane;c<DWg;c+=64) d[c]=s[c];
    } else {
      const float* s=(const float*)embw + (long long)idx*DWg;
      for(int c=lane;c<DWg;c+=64) d[c]=f2b(s[c]);
    }
    if(lane<2) d[350+lane]=0;
    return;
  }
  int gid = (bx-8192)*256 + tid;
  int w = gid/50, f = gid - w*50;
  int ch[20];
  #pragma unroll
  for(int r=0;r<20;r++) ch[r]=ldi(chars,(long long)w*LWW+r,i64);
  float acc[22];
  #pragma unroll
  for(int t=0;t<22;t++) acc[t]=0.f;
  for(int c=0;c<25;c++){
    float wv0=cw[(f*3+0)*25+c];
    float wv1=cw[(f*3+1)*25+c];
    float wv2=cw[(f*3+2)*25+c];
    #pragma unroll
    for(int r=0;r<20;r++){
      float xv = ec[ch[r]*25+c];
      acc[r+2] += xv*wv0;
      acc[r+1] += xv*wv1;
      acc[r]   += xv*wv2;
    }
  }
  float m=-1e30f;
  #pragma unroll
  for(int t=0;t<22;t++) m=fmaxf(m,acc[t]);
  feats[(size_t)w*KP + 300 + f] = f2b(m + cb[f]);
}

// ---------------- merged x-gate GEMM (both dirs, MFMA 128x128) ----------------
__global__ __launch_bounds__(256) void k_gemm(const u16* __restrict__ feats,
                      const u16* __restrict__ wihF, const float* __restrict__ biasF,
                      const u16* __restrict__ wihB, const float* __restrict__ biasB,
                      u16* __restrict__ xgF, u16* __restrict__ xgB){
  __shared__ u16 At[128*40];
  __shared__ u16 Bt[128*40];
  int tid=threadIdx.x, m0=blockIdx.x*128;
  int half = (blockIdx.y>=7);
  int n0 = (blockIdx.y - (half?7:0))*128;
  const u16* wih = half? wihB : wihF;
  const float* bias = half? biasB : biasF;
  u16* xg = half? xgB : xgF;
  int wv=tid>>6, lane=tid&63;
  int wr=(wv>>1)*64, wc=(wv&1)*64;
  const f32x4 z4={0.f,0.f,0.f,0.f};
  f32x4 acc[4][4];
  #pragma unroll
  for(int a=0;a<4;a++){ acc[a][0]=z4; acc[a][1]=z4; acc[a][2]=z4; acc[a][3]=z4; }
  int row=tid>>2, grp=tid&3;
  for(int kt=0;kt<11;kt++){
    int k0=kt*32;
    #pragma unroll
    for(int p=0;p<2;p++){
      int r=row+p*64;
      *(int4*)&At[r*40+grp*8] = *(const int4*)&feats[(size_t)(m0+r)*KP + k0 + grp*8];
      *(int4*)&Bt[r*40+grp*8] = *(const int4*)&wih  [(size_t)(n0+r)*KP + k0 + grp*8];
    }
    __syncthreads();
    bf16x8 af[4], bg[4];
    #pragma unroll
    for(int ri=0;ri<4;ri++) af[ri]=*(const bf16x8*)&At[(wr+ri*16+(lane&15))*40 + ((lane>>4)<<3)];
    #pragma unroll
    for(int ni=0;ni<4;ni++) bg[ni]=*(const bf16x8*)&Bt[(wc+ni*16+(lane&15))*40 + ((lane>>4)<<3)];
    #pragma unroll
    for(int ri=0;ri<4;ri++)
      #pragma unroll
      for(int ni=0;ni<4;ni++) acc[ri][ni]=mfma16(af[ri],bg[ni],acc[ri][ni]);
    __syncthreads();
  }
  #pragma unroll
  for(int ni=0;ni<4;ni++){
    int n = n0 + wc + ni*16 + (lane&15);
    if(n>=G4) continue;
    float bv = bias[n];
    int g4=n/200, j=n-g4*200;
    #pragma unroll
    for(int ri=0;ri<4;ri++)
      #pragma unroll
      for(int rr=0;rr<4;rr++){
        int m = m0 + wr + ri*16 + ((lane>>4)&3)*4 + rr;
        int b = m>>8, s = m&255;
        xg[((size_t)s*BB + b)*G4 + j*4 + g4] = f2b(acc[ri][ni][rr] + bv);
      }
  }
}

// ---------------- BiLSTM recurrence (r16 template + TOP-of-step prefetch) ----
__device__ __forceinline__ void lstm_upd(int lane, int t, int lenv,
    f32x4 a, u16x4 xrv, float& cstv, float& hregv,
    u16* __restrict__ enc, int eoffv, u16* hnp, int hboffv){
  float v0=a[0], v1=a[1], v2=a[2], v3=a[3];
  float f0,f1,r0,r1;
  const bool hi2=(lane&2)!=0;
  f0 = hi2? v0:v2; f1 = hi2? v1:v3;
  r0=__shfl_xor(f0,2); r1=__shfl_xor(f1,2);
  if(hi2){v0=r0;v1=r1;} else {v2=r0;v3=r1;}
  const bool hi1=(lane&1)!=0;
  f0 = hi1? v0:v1; f1 = hi1? v2:v3;
  r0=__shfl_xor(f0,1); r1=__shfl_xor(f1,1);
  if(hi1){v0=r0;v2=r1;} else {v1=r0;v3=r1;}
  float gi=v0+b2f(xrv.x), gf=v1+b2f(xrv.y);
  float gg=v2+b2f(xrv.z), go=v3+b2f(xrv.w);
  float iv=sigf(gi), fv=sigf(gf), gv=tanhf_(gg), ov=sigf(go);
  float cn=fv*cstv+iv*gv;
  float hv=ov*tanhf_(cn);
  const bool m = t<lenv;
  if(m){ cstv=cn; hregv=hv; }
  enc[(size_t)eoffv + (size_t)t*(2*HWg)] = m? f2b(hv):(u16)0;
  hnp[hboffv] = f2b(hregv);
}

__global__ __launch_bounds__(512,1) void k_lstm(
    const u16* __restrict__ xgf, const u16* __restrict__ xgb,
    const u16* __restrict__ whhf, const u16* __restrict__ whhb,
    const void* __restrict__ lens, u16* __restrict__ enc,
    const int* __restrict__ iflag)
{
  __shared__ u16 hbuf[2][16*232];
  __shared__ int len_s[16];
  __shared__ u16 wlds[7168];

  const int blk=blockIdx.x, dir=blk&1, b0=(blk>>1)*16;
  const u16* xg  = dir? xgb : xgf;
  const u16* whh = dir? whhb : whhf;
  const int tid=threadIdx.x, wv=tid>>6, lane=tid&63;
  const int i64=*iflag;

  for(int i=tid;i<2*16*232;i+=512) ((u16*)hbuf)[i]=0;
  if(tid<16) len_s[tid]=ldi(lens,b0+tid,i64);
  for(int i=tid;i<7168;i+=512) wlds[i]=whh[48*3584 + i];

  bf16x8 wf[6][7];
  #pragma unroll
  for(int i=0;i<6;i++)
    #pragma unroll
    for(int ks=0;ks<7;ks++)
      wf[i][ks]=*(const bf16x8*)&whh[(size_t)((wv*6+i)*7+ks)*512 + lane*8];

  const int bl = ((lane>>4)<<2) + (lane&3);       // 0..15
  const int jl = (lane>>2)&3;
  __syncthreads();
  const int lenv = len_s[bl];

  int xoff[7], eoff[7], hboff[7];
  #pragma unroll
  for(int q=0;q<6;q++){
    int j=(wv*6+q)*4+jl;
    xoff[q]=(b0+bl)*G4 + j*4;
    eoff[q]=((b0+bl)*SS)*(2*HWg) + dir*HWg + j;
    hboff[q]=bl*232 + j;
  }
  { int j=(48+wv)*4+jl;
    xoff[6]=(b0+bl)*G4 + j*4;
    eoff[6]=((b0+bl)*SS)*(2*HWg) + dir*HWg + j;
    hboff[6]=bl*232 + j; }

  float cst[7]={0,0,0,0,0,0,0}, hreg[7]={0,0,0,0,0,0,0};
  u16x4 xr[7];
  {
    const int t0 = dir? (SS-1):0;
    const size_t tb=(size_t)t0*(BB*G4);
    #pragma unroll
    for(int q=0;q<6;q++) xr[q]=*(const u16x4*)&xg[tb+xoff[q]];
    if(wv<2) xr[6]=*(const u16x4*)&xg[tb+xoff[6]];
  }

  const f32x4 z4={0.f,0.f,0.f,0.f};
  int cur=0;
  for(int step=0; step<SS; ++step){
    const int t = dir ? (SS-1-step) : step;
    int sn = step+1; if(sn>SS-1) sn=SS-1;
    const int tn = dir ? (SS-1-sn) : sn;
    const size_t tbn=(size_t)tn*(BB*G4);
    const u16* hc = hbuf[cur];
    u16* hn_ = hbuf[cur^1];

    // TOP-of-step prefetch: next step's xg, issued before MFMA so the
    // barrier's vmcnt(0) drain finds them already complete.
    u16x4 xrn[7];
    #pragma unroll
    for(int q=0;q<6;q++) xrn[q]=*(const u16x4*)&xg[tbn+xoff[q]];
    if(wv<2) xrn[6]=*(const u16x4*)&xg[tbn+xoff[6]];

    bf16x8 afr[7];
    #pragma unroll
    for(int ks=0;ks<7;ks++)
      afr[ks]=*(const bf16x8*)&hc[(lane&15)*232 + ks*32 + ((lane>>4)<<3)];

    f32x4 acc[7];
    #pragma unroll
    for(int i=0;i<6;i++){
      acc[i]=z4;
      #pragma unroll
      for(int ks=0;ks<7;ks++) acc[i]=mfma16(afr[ks],wf[i][ks],acc[i]);
    }
    acc[6]=z4;
    if(wv<2){
      #pragma unroll
      for(int ks=0;ks<7;ks++){
        bf16x8 bw=*(const bf16x8*)&wlds[(wv*7+ks)*512 + lane*8];
        acc[6]=mfma16(afr[ks],bw,acc[6]);
      }
    }

    #pragma unroll
    for(int q=0;q<6;q++)
      lstm_upd(lane,t,lenv,acc[q],xr[q],cst[q],hreg[q],enc,eoff[q],hn_,hboff[q]);
    if(wv<2)
      lstm_upd(lane,t,lenv,acc[6],xr[6],cst[6],hreg[6],enc,eoff[6],hn_,hboff[6]);

    #pragma unroll
    for(int q=0;q<7;q++) xr[q]=xrn[q];

    __syncthreads();                              // single barrier per step
    cur^=1;
  }
}

// ---------------- emissions: FLOAT32 output ----------------------------------
__global__ __launch_bounds__(256) void k_emis(const u16* __restrict__ enc,
                      const float* __restrict__ pw_g, const float* __restrict__ pb,
                      float* __restrict__ out){
  __shared__ float pw[10*404];
  int tid=threadIdx.x;
  for(int i=tid;i<4000;i+=256){ int tg=i/400,h=i-tg*400; pw[tg*404+h]=pw_g[i]; }
  __syncthreads();
  int idx = blockIdx.x*256 + tid;                 // 327680 outputs
  int bs = idx/NTg, tg = idx-bs*NTg;
  const u16* er = enc + (size_t)bs*(2*HWg);
  float acc=0.f;
  #pragma unroll 4
  for(int h=0;h<400;h+=4){
    u16x4 v=*(const u16x4*)&er[h];
    acc += b2f(v.x)*pw[tg*404+h]   + b2f(v.y)*pw[tg*404+h+1]
         + b2f(v.z)*pw[tg*404+h+2] + b2f(v.w)*pw[tg*404+h+3];
  }
  out[idx] = acc + pb[tg];                        // f32 write
}

// ---------------- launch -----------------------------------------------------
extern "C" void kernel_launch(void* const* d_in, const int* in_sizes, int n_in,
                              void* d_out, int out_size, void* d_ws, size_t ws_size,
                              hipStream_t stream){
  float* out=(float*)d_out;
  if(n_in!=15){ k_diag<<<1280,256,0,stream>>>(out, 20480.f); return; }
  if(out_size!=OUTN){ k_diag<<<1280,256,0,stream>>>(out, 24576.f); return; }

  const void* words=d_in[0];
  const void* chars=d_in[1];
  const void* lens =d_in[2];
  const void* echar=d_in[3];
  const void* embw =d_in[4];
  const void* convw=d_in[5];
  const void* convb=d_in[6];
  const void* wihf =d_in[7];
  const void* whhf =d_in[8];
  const void* bfp  =d_in[9];
  const void* wihb =d_in[10];
  const void* whhb =d_in[11];
  const void* bbp  =d_in[12];
  const void* pw   =d_in[13];
  const void* pb   =d_in[14];

  char* ws=(char*)d_ws;
  size_t cur=0;
  auto alloc=[&](size_t sz){ size_t o=cur; cur=(cur+sz+255)&~(size_t)255; return o; };
  size_t oF    = alloc(4);
  size_t oIF   = alloc(4);
  size_t oWIHF = alloc((size_t)NP*KP*2);
  size_t oWIHB = alloc((size_t)NP*KP*2);
  size_t oWHHF = alloc(179200*2);
  size_t oWHHB = alloc(179200*2);
  size_t oEC   = alloc(2025*4);
  size_t oCW   = alloc(3750*4);
  size_t oCB   = alloc(64*4);
  size_t oBF   = alloc(800*4);
  size_t oBB   = alloc(800*4);
  size_t oPW   = alloc(4000*4);
  size_t oPB   = alloc(16*4);
  size_t oSH   = alloc((size_t)NW*2*HWg*2);       // feats / enc alias (bf16)
  size_t oXGF  = alloc((size_t)SS*BB*G4*2);
  size_t oXGB  = alloc((size_t)SS*BB*G4*2);
  size_t need  = cur;

  if(ws_size < need){
    k_diag<<<1280,256,0,stream>>>(out, 16384.f + 64.f*(float)(ws_size>>20));
    return;
  }

  int*   flag =(int*)(ws+oF);
  int*   iflag=(int*)(ws+oIF);
  u16*   sWIHF=(u16*)(ws+oWIHF);
  u16*   sWIHB=(u16*)(ws+oWIHB);
  u16*   sWHHF=(u16*)(ws+oWHHF);
  u16*   sWHHB=(u16*)(ws+oWHHB);
  float* sEC  =(float*)(ws+oEC);
  float* sCW  =(float*)(ws+oCW);
  float* sCB  =(float*)(ws+oCB);
  float* sBF  =(float*)(ws+oBF);
  float* sBB  =(float*)(ws+oBB);
  float* sPW  =(float*)(ws+oPW);
  float* sPB  =(float*)(ws+oPB);
  u16*   feats=(u16*)(ws+oSH);
  u16*   enc  =(u16*)(ws+oSH);                    // alias (feats dead post-GEMM)
  u16*   xgfp =(u16*)(ws+oXGF);
  u16*   xgbp =(u16*)(ws+oXGB);

  k_probes<<<1,128,0,stream>>>(embw, (const int*)words, flag, iflag);
  k_stage<<<3909,256,0,stream>>>(wihf, wihb, whhf, whhb,
                                 echar, convw, convb, bfp, bbp, pw, pb,
                                 sWIHF, sWIHB, sWHHF, sWHHB,
                                 sEC, sCW, sCB, sBF, sBB, sPW, sPB, flag);
  k_feats<<<14592,256,0,stream>>>(words, chars, embw, sEC, sCW, sCB,
                                  feats, flag, iflag);
  k_gemm<<<dim3(256,14),256,0,stream>>>(feats, sWIHF, sBF, sWIHB, sBB, xgfp, xgbp);
  k_lstm<<<16,512,0,stream>>>(xgfp, xgbp, sWHHF, sWHHB, lens, enc, iflag);
  k_emis<<<1280,256,0,stream>>>(enc, sPW, sPB, out);
}

// Round 21
// 1612.908 us; speedup vs baseline: 1.1983x; 1.1983x over previous
//
#include <hip/hip_runtime.h>

typedef unsigned short u16;
typedef __attribute__((ext_vector_type(4))) unsigned short u16x4;
typedef __attribute__((ext_vector_type(8))) short bf16x8;
typedef __attribute__((ext_vector_type(4))) float f32x4;

#define BB 128
#define SS 256
#define LWW 20
#define NTg 10
#define HWg 200
#define G4 800
#define DWg 300
#define DIN 350
#define KP 352
#define NP 896
#define NW (BB*SS)
#define OUTN (NW*NTg)

__device__ __forceinline__ float b2f(u16 u){ return __uint_as_float(((unsigned)u)<<16); }
__device__ __forceinline__ u16 f2b(float f){
  unsigned x = __float_as_uint(f);
  unsigned r = (x + 0x7fffu + ((x>>16)&1u)) >> 16;
  return (u16)r;
}
__device__ __forceinline__ float ldf(const void* p, long long i, int isb){
  return isb ? b2f(((const u16*)p)[i]) : ((const float*)p)[i];
}
__device__ __forceinline__ int ldi(const void* p, long long i, int i64){
  return i64 ? (int)((const long long*)p)[i] : ((const int*)p)[i];
}
__device__ __forceinline__ f32x4 mfma16(bf16x8 a, bf16x8 b, f32x4 c){
  return __builtin_amdgcn_mfma_f32_16x16x32_bf16(a,b,c,0,0,0);
}
__device__ __forceinline__ float sigf(float x){
  return __builtin_amdgcn_rcpf(1.f + __expf(-x));
}
__device__ __forceinline__ float tanhf_(float x){
  return 1.f - 2.f*__builtin_amdgcn_rcpf(1.f + __expf(2.f*x));
}

// ---------------- diagnostic --------------------------------------------------
__global__ void k_diag(float* out, float code){
  int i = blockIdx.x*256 + threadIdx.x;
  if(i<OUTN) out[i]=code;
}

// ---------------- fused probes ------------------------------------------------
__global__ void k_probes(const void* p, const int* __restrict__ words,
                         int* flag, int* iflag){
  __shared__ int cnt, zc;
  if(threadIdx.x==0){ cnt=0; zc=0; }
  __syncthreads();
  float a = fabsf(b2f(((const u16*)p)[threadIdx.x]));
  if(a>1e-5f && a<1.0f) atomicAdd(&cnt,1);
  if(threadIdx.x<64){
    int z=0;
    for(int k=threadIdx.x;k<128;k+=64)
      if(words[2*k+1]==0) z++;
    atomicAdd(&zc,z);
  }
  __syncthreads();
  if(threadIdx.x==0){ *flag=(cnt>=100)?1:0; *iflag=(zc>=100)?1:0; }
}

// ---------------- mega staging kernel (range-dispatched) ----------------------
__device__ __forceinline__ void st_wih(const void* src, u16* dst, int isb, int i){
  if(i>=NP*KP) return;
  int n=i/KP, k=i-n*KP;
  float v = (n<G4 && k<DIN) ? ldf(src,(long long)n*DIN+k,isb) : 0.f;
  dst[i]=f2b(v);
}
// w_hh -> MFMA B-frags, INTERLEAVED row order n' = j*4+gate (r16 layout)
__device__ __forceinline__ void st_whh(const void* src, u16* dst, int isb, int i){
  if(i>=179200) return;
  int tile=i/3584, r=i%3584, ks=r/512, r2=r%512, l=r2/8, jreg=r2%8;
  int c = tile*16 + (l&15);
  int j = c>>2, gate = c&3;
  int n = gate*200 + j;
  int k = ks*32 + ((l>>4)<<3) + jreg;
  float v = (k<HWg)? ldf(src,(long long)n*HWg+k,isb) : 0.f;
  dst[i]=f2b(v);
}
__global__ void k_stage(const void* wihf, const void* wihb,
                        const void* whhf, const void* whhb,
                        const void* echar, const void* convw, const void* cb,
                        const void* bfp, const void* bbp, const void* pw, const void* pb,
                        u16* dWIHF, u16* dWIHB, u16* dWHHF, u16* dWHHB,
                        float* d_ec, float* d_cw, float* d_cb,
                        float* d_bf, float* d_bb, float* d_pw, float* d_pb,
                        const int* __restrict__ flag){
  int isb=*flag;
  int bx=blockIdx.x, tid=threadIdx.x;
  if(bx<1232){ st_wih(wihf,dWIHF,isb,bx*256+tid); return; }
  bx-=1232;
  if(bx<1232){ st_wih(wihb,dWIHB,isb,bx*256+tid); return; }
  bx-=1232;
  if(bx<700){ st_whh(whhf,dWHHF,isb,bx*256+tid); return; }
  bx-=700;
  if(bx<700){ st_whh(whhb,dWHHB,isb,bx*256+tid); return; }
  bx-=700;
  int i = bx*256 + tid;
  if(i<2025){ d_ec[i]=ldf(echar,i,isb); return; } i-=2025;   // 81*25
  if(i<3750){ d_cw[i]=ldf(convw,i,isb); return; } i-=3750;   // 50*3*25
  if(i<64){ d_cb[i]=(i<50)?ldf(cb,i,isb):0.f; return; } i-=64;
  if(i<800){ d_bf[i]=ldf(bfp,i,isb); return; } i-=800;
  if(i<800){ d_bb[i]=ldf(bbp,i,isb); return; } i-=800;
  if(i<4000){ d_pw[i]=ldf(pw,i,isb); return; } i-=4000;
  if(i<16){ d_pb[i]=(i<10)?ldf(pb,i,isb):0.f; return; }
}

// ---------------- fused feats: word-emb gather + char CNN --------------------
__global__ __launch_bounds__(256) void k_feats(const void* __restrict__ words,
                      const void* __restrict__ chars, const void* __restrict__ embw,
                      const float* __restrict__ ec, const float* __restrict__ cw,
                      const float* __restrict__ cb, u16* __restrict__ feats,
                      const int* __restrict__ flag, const int* __restrict__ iflag){
  int isb=*flag, i64=*iflag;
  int bx=blockIdx.x, tid=threadIdx.x;
  if(bx<8192){
    int wv=tid>>6, lane=tid&63;
    int row = bx*4 + wv;
    int idx = ldi(words,row,i64);
    u16* d = feats + (size_t)row*KP;
    if(isb){
      const u16* s=(const u16*)embw + (long long)idx*DWg;
      for(int c=lane;c<DWg;c+=64) d[c]=s[c];
    } else {
      const float* s=(const float*)embw + (long long)idx*DWg;
      for(int c=lane;c<DWg;c+=64) d[c]=f2b(s[c]);
    }
    if(lane<2) d[350+lane]=0;
    return;
  }
  int gid = (bx-8192)*256 + tid;
  int w = gid/50, f = gid - w*50;
  int ch[20];
  #pragma unroll
  for(int r=0;r<20;r++) ch[r]=ldi(chars,(long long)w*LWW+r,i64);
  float acc[22];
  #pragma unroll
  for(int t=0;t<22;t++) acc[t]=0.f;
  for(int c=0;c<25;c++){
    float wv0=cw[(f*3+0)*25+c];
    float wv1=cw[(f*3+1)*25+c];
    float wv2=cw[(f*3+2)*25+c];
    #pragma unroll
    for(int r=0;r<20;r++){
      float xv = ec[ch[r]*25+c];
      acc[r+2] += xv*wv0;
      acc[r+1] += xv*wv1;
      acc[r]   += xv*wv2;
    }
  }
  float m=-1e30f;
  #pragma unroll
  for(int t=0;t<22;t++) m=fmaxf(m,acc[t]);
  feats[(size_t)w*KP + 300 + f] = f2b(m + cb[f]);
}

// ---------------- merged x-gate GEMM (both dirs, MFMA 128x128) ----------------
__global__ __launch_bounds__(256) void k_gemm(const u16* __restrict__ feats,
                      const u16* __restrict__ wihF, const float* __restrict__ biasF,
                      const u16* __restrict__ wihB, const float* __restrict__ biasB,
                      u16* __restrict__ xgF, u16* __restrict__ xgB){
  __shared__ u16 At[128*40];
  __shared__ u16 Bt[128*40];
  int tid=threadIdx.x, m0=blockIdx.x*128;
  int half = (blockIdx.y>=7);
  int n0 = (blockIdx.y - (half?7:0))*128;
  const u16* wih = half? wihB : wihF;
  const float* bias = half? biasB : biasF;
  u16* xg = half? xgB : xgF;
  int wv=tid>>6, lane=tid&63;
  int wr=(wv>>1)*64, wc=(wv&1)*64;
  const f32x4 z4={0.f,0.f,0.f,0.f};
  f32x4 acc[4][4];
  #pragma unroll
  for(int a=0;a<4;a++){ acc[a][0]=z4; acc[a][1]=z4; acc[a][2]=z4; acc[a][3]=z4; }
  int row=tid>>2, grp=tid&3;
  for(int kt=0;kt<11;kt++){
    int k0=kt*32;
    #pragma unroll
    for(int p=0;p<2;p++){
      int r=row+p*64;
      *(int4*)&At[r*40+grp*8] = *(const int4*)&feats[(size_t)(m0+r)*KP + k0 + grp*8];
      *(int4*)&Bt[r*40+grp*8] = *(const int4*)&wih  [(size_t)(n0+r)*KP + k0 + grp*8];
    }
    __syncthreads();
    bf16x8 af[4], bg[4];
    #pragma unroll
    for(int ri=0;ri<4;ri++) af[ri]=*(const bf16x8*)&At[(wr+ri*16+(lane&15))*40 + ((lane>>4)<<3)];
    #pragma unroll
    for(int ni=0;ni<4;ni++) bg[ni]=*(const bf16x8*)&Bt[(wc+ni*16+(lane&15))*40 + ((lane>>4)<<3)];
    #pragma unroll
    for(int ri=0;ri<4;ri++)
      #pragma unroll
      for(int ni=0;ni<4;ni++) acc[ri][ni]=mfma16(af[ri],bg[ni],acc[ri][ni]);
    __syncthreads();
  }
  #pragma unroll
  for(int ni=0;ni<4;ni++){
    int n = n0 + wc + ni*16 + (lane&15);
    if(n>=G4) continue;
    float bv = bias[n];
    int g4=n/200, j=n-g4*200;
    #pragma unroll
    for(int ri=0;ri<4;ri++)
      #pragma unroll
      for(int rr=0;rr<4;rr++){
        int m = m0 + wr + ri*16 + ((lane>>4)&3)*4 + rr;
        int b = m>>8, s = m&255;
        xg[((size_t)s*BB + b)*G4 + j*4 + g4] = f2b(acc[ri][ni][rr] + bv);
      }
  }
}

// ---------------- BiLSTM recurrence (r16/r19 variant: best measured) ---------
__device__ __forceinline__ void lstm_upd(int lane, int t, int lenv,
    f32x4 a, u16x4 xrv, float& cstv, float& hregv,
    u16* __restrict__ enc, int eoffv, u16* hnp, int hboffv){
  float v0=a[0], v1=a[1], v2=a[2], v3=a[3];
  float f0,f1,r0,r1;
  const bool hi2=(lane&2)!=0;
  f0 = hi2? v0:v2; f1 = hi2? v1:v3;
  r0=__shfl_xor(f0,2); r1=__shfl_xor(f1,2);
  if(hi2){v0=r0;v1=r1;} else {v2=r0;v3=r1;}
  const bool hi1=(lane&1)!=0;
  f0 = hi1? v0:v1; f1 = hi1? v2:v3;
  r0=__shfl_xor(f0,1); r1=__shfl_xor(f1,1);
  if(hi1){v0=r0;v2=r1;} else {v1=r0;v3=r1;}
  float gi=v0+b2f(xrv.x), gf=v1+b2f(xrv.y);
  float gg=v2+b2f(xrv.z), go=v3+b2f(xrv.w);
  float iv=sigf(gi), fv=sigf(gf), gv=tanhf_(gg), ov=sigf(go);
  float cn=fv*cstv+iv*gv;
  float hv=ov*tanhf_(cn);
  const bool m = t<lenv;
  if(m){ cstv=cn; hregv=hv; }
  enc[(size_t)eoffv + (size_t)t*(2*HWg)] = m? f2b(hv):(u16)0;
  hnp[hboffv] = f2b(hregv);
}

__global__ __launch_bounds__(512,1) void k_lstm(
    const u16* __restrict__ xgf, const u16* __restrict__ xgb,
    const u16* __restrict__ whhf, const u16* __restrict__ whhb,
    const void* __restrict__ lens, u16* __restrict__ enc,
    const int* __restrict__ iflag)
{
  __shared__ u16 hbuf[2][16*232];
  __shared__ int len_s[16];
  __shared__ u16 wlds[7168];

  const int blk=blockIdx.x, dir=blk&1, b0=(blk>>1)*16;
  const u16* xg  = dir? xgb : xgf;
  const u16* whh = dir? whhb : whhf;
  const int tid=threadIdx.x, wv=tid>>6, lane=tid&63;
  const int i64=*iflag;

  for(int i=tid;i<2*16*232;i+=512) ((u16*)hbuf)[i]=0;
  if(tid<16) len_s[tid]=ldi(lens,b0+tid,i64);
  for(int i=tid;i<7168;i+=512) wlds[i]=whh[48*3584 + i];

  bf16x8 wf[6][7];
  #pragma unroll
  for(int i=0;i<6;i++)
    #pragma unroll
    for(int ks=0;ks<7;ks++)
      wf[i][ks]=*(const bf16x8*)&whh[(size_t)((wv*6+i)*7+ks)*512 + lane*8];

  const int bl = ((lane>>4)<<2) + (lane&3);       // 0..15
  const int jl = (lane>>2)&3;
  __syncthreads();
  const int lenv = len_s[bl];

  int xoff[7], eoff[7], hboff[7];
  #pragma unroll
  for(int q=0;q<6;q++){
    int j=(wv*6+q)*4+jl;
    xoff[q]=(b0+bl)*G4 + j*4;
    eoff[q]=((b0+bl)*SS)*(2*HWg) + dir*HWg + j;
    hboff[q]=bl*232 + j;
  }
  { int j=(48+wv)*4+jl;
    xoff[6]=(b0+bl)*G4 + j*4;
    eoff[6]=((b0+bl)*SS)*(2*HWg) + dir*HWg + j;
    hboff[6]=bl*232 + j; }

  float cst[7]={0,0,0,0,0,0,0}, hreg[7]={0,0,0,0,0,0,0};
  u16x4 xr[7];
  {
    const int t0 = dir? (SS-1):0;
    const size_t tb=(size_t)t0*(BB*G4);
    #pragma unroll
    for(int q=0;q<6;q++) xr[q]=*(const u16x4*)&xg[tb+xoff[q]];
    if(wv<2) xr[6]=*(const u16x4*)&xg[tb+xoff[6]];
  }

  const f32x4 z4={0.f,0.f,0.f,0.f};
  int cur=0;
  for(int step=0; step<SS; ++step){
    const int t = dir ? (SS-1-step) : step;
    int sn = step+1; if(sn>SS-1) sn=SS-1;
    const int tn = dir ? (SS-1-sn) : sn;
    const size_t tbn=(size_t)tn*(BB*G4);
    const u16* hc = hbuf[cur];
    u16* hn_ = hbuf[cur^1];

    bf16x8 afr[7];
    #pragma unroll
    for(int ks=0;ks<7;ks++)
      afr[ks]=*(const bf16x8*)&hc[(lane&15)*232 + ks*32 + ((lane>>4)<<3)];

    f32x4 acc[7];
    #pragma unroll
    for(int i=0;i<6;i++){
      acc[i]=z4;
      #pragma unroll
      for(int ks=0;ks<7;ks++) acc[i]=mfma16(afr[ks],wf[i][ks],acc[i]);
    }
    acc[6]=z4;
    if(wv<2){
      #pragma unroll
      for(int ks=0;ks<7;ks++){
        bf16x8 bw=*(const bf16x8*)&wlds[(wv*7+ks)*512 + lane*8];
        acc[6]=mfma16(afr[ks],bw,acc[6]);
      }
    }

    #pragma unroll
    for(int q=0;q<6;q++){
      lstm_upd(lane,t,lenv,acc[q],xr[q],cst[q],hreg[q],enc,eoff[q],hn_,hboff[q]);
      xr[q]=*(const u16x4*)&xg[tbn+xoff[q]];
    }
    if(wv<2){
      lstm_upd(lane,t,lenv,acc[6],xr[6],cst[6],hreg[6],enc,eoff[6],hn_,hboff[6]);
      xr[6]=*(const u16x4*)&xg[tbn+xoff[6]];
    }

    __syncthreads();                              // single barrier per step
    cur^=1;
  }
}

// ---------------- emissions: one thread per (b,s) row, f32 output ------------
__global__ __launch_bounds__(256) void k_emis(const u16* __restrict__ enc,
                      const float* __restrict__ pw_g, const float* __restrict__ pb,
                      float* __restrict__ out){
  __shared__ float pw[10*404];
  __shared__ float pbs[16];
  int tid=threadIdx.x;
  for(int i=tid;i<4000;i+=256){ int tg=i/400,h=i-tg*400; pw[tg*404+h]=pw_g[i]; }
  if(tid<10) pbs[tid]=pb[tid];
  __syncthreads();
  int bs = blockIdx.x*256 + tid;                  // 32768 rows (128 blocks)
  const u16* er = enc + (size_t)bs*(2*HWg);
  float acc[10];
  #pragma unroll
  for(int tg=0;tg<10;tg++) acc[tg]=pbs[tg];
  for(int h=0;h<400;h+=4){
    u16x4 v=*(const u16x4*)&er[h];
    float e0=b2f(v.x), e1=b2f(v.y), e2=b2f(v.z), e3=b2f(v.w);
    #pragma unroll
    for(int tg=0;tg<10;tg++)
      acc[tg] += e0*pw[tg*404+h]   + e1*pw[tg*404+h+1]
               + e2*pw[tg*404+h+2] + e3*pw[tg*404+h+3];
  }
  float* o = out + (size_t)bs*10;
  #pragma unroll
  for(int tg=0;tg<10;tg++) o[tg]=acc[tg];
}

// ---------------- launch -----------------------------------------------------
extern "C" void kernel_launch(void* const* d_in, const int* in_sizes, int n_in,
                              void* d_out, int out_size, void* d_ws, size_t ws_size,
                              hipStream_t stream){
  float* out=(float*)d_out;
  if(n_in!=15){ k_diag<<<1280,256,0,stream>>>(out, 20480.f); return; }
  if(out_size!=OUTN){ k_diag<<<1280,256,0,stream>>>(out, 24576.f); return; }

  const void* words=d_in[0];
  const void* chars=d_in[1];
  const void* lens =d_in[2];
  const void* echar=d_in[3];
  const void* embw =d_in[4];
  const void* convw=d_in[5];
  const void* convb=d_in[6];
  const void* wihf =d_in[7];
  const void* whhf =d_in[8];
  const void* bfp  =d_in[9];
  const void* wihb =d_in[10];
  const void* whhb =d_in[11];
  const void* bbp  =d_in[12];
  const void* pw   =d_in[13];
  const void* pb   =d_in[14];

  char* ws=(char*)d_ws;
  size_t cur=0;
  auto alloc=[&](size_t sz){ size_t o=cur; cur=(cur+sz+255)&~(size_t)255; return o; };
  size_t oF    = alloc(4);
  size_t oIF   = alloc(4);
  size_t oWIHF = alloc((size_t)NP*KP*2);
  size_t oWIHB = alloc((size_t)NP*KP*2);
  size_t oWHHF = alloc(179200*2);
  size_t oWHHB = alloc(179200*2);
  size_t oEC   = alloc(2025*4);
  size_t oCW   = alloc(3750*4);
  size_t oCB   = alloc(64*4);
  size_t oBF   = alloc(800*4);
  size_t oBB   = alloc(800*4);
  size_t oPW   = alloc(4000*4);
  size_t oPB   = alloc(16*4);
  size_t oSH   = alloc((size_t)NW*2*HWg*2);       // feats / enc alias (bf16)
  size_t oXGF  = alloc((size_t)SS*BB*G4*2);
  size_t oXGB  = alloc((size_t)SS*BB*G4*2);
  size_t need  = cur;

  if(ws_size < need){
    k_diag<<<1280,256,0,stream>>>(out, 16384.f + 64.f*(float)(ws_size>>20));
    return;
  }

  int*   flag =(int*)(ws+oF);
  int*   iflag=(int*)(ws+oIF);
  u16*   sWIHF=(u16*)(ws+oWIHF);
  u16*   sWIHB=(u16*)(ws+oWIHB);
  u16*   sWHHF=(u16*)(ws+oWHHF);
  u16*   sWHHB=(u16*)(ws+oWHHB);
  float* sEC  =(float*)(ws+oEC);
  float* sCW  =(float*)(ws+oCW);
  float* sCB  =(float*)(ws+oCB);
  float* sBF  =(float*)(ws+oBF);
  float* sBB  =(float*)(ws+oBB);
  float* sPW  =(float*)(ws+oPW);
  float* sPB  =(float*)(ws+oPB);
  u16*   feats=(u16*)(ws+oSH);
  u16*   enc  =(u16*)(ws+oSH);                    // alias (feats dead post-GEMM)
  u16*   xgfp =(u16*)(ws+oXGF);
  u16*   xgbp =(u16*)(ws+oXGB);

  k_probes<<<1,128,0,stream>>>(embw, (const int*)words, flag, iflag);
  k_stage<<<3909,256,0,stream>>>(wihf, wihb, whhf, whhb,
                                 echar, convw, convb, bfp, bbp, pw, pb,
                                 sWIHF, sWIHB, sWHHF, sWHHB,
                                 sEC, sCW, sCB, sBF, sBB, sPW, sPB, flag);
  k_feats<<<14592,256,0,stream>>>(words, chars, embw, sEC, sCW, sCB,
                                  feats, flag, iflag);
  k_gemm<<<dim3(256,14),256,0,stream>>>(feats, sWIHF, sBF, sWIHB, sBB, xgfp, xgbp);
  k_lstm<<<16,512,0,stream>>>(xgfp, xgbp, sWHHF, sWHHB, lens, enc, iflag);
  k_emis<<<128,256,0,stream>>>(enc, sPW, sPB, out);
}

// Round 22
// 1569.898 us; speedup vs baseline: 1.2312x; 1.0274x over previous
//
#include <hip/hip_runtime.h>

typedef unsigned short u16;
typedef __attribute__((ext_vector_type(4))) unsigned short u16x4;
typedef __attribute__((ext_vector_type(8))) short bf16x8;
typedef __attribute__((ext_vector_type(4))) float f32x4;

#define BB 128
#define SS 256
#define LWW 20
#define NTg 10
#define HWg 200
#define G4 800
#define DWg 300
#define DIN 350
#define KP 352
#define NP 896
#define NW (BB*SS)
#define OUTN (NW*NTg)

__device__ __forceinline__ float b2f(u16 u){ return __uint_as_float(((unsigned)u)<<16); }
__device__ __forceinline__ u16 f2b(float f){
  unsigned x = __float_as_uint(f);
  unsigned r = (x + 0x7fffu + ((x>>16)&1u)) >> 16;
  return (u16)r;
}
__device__ __forceinline__ float ldf(const void* p, long long i, int isb){
  return isb ? b2f(((const u16*)p)[i]) : ((const float*)p)[i];
}
__device__ __forceinline__ int ldi(const void* p, long long i, int i64){
  return i64 ? (int)((const long long*)p)[i] : ((const int*)p)[i];
}
__device__ __forceinline__ f32x4 mfma16(bf16x8 a, bf16x8 b, f32x4 c){
  return __builtin_amdgcn_mfma_f32_16x16x32_bf16(a,b,c,0,0,0);
}
__device__ __forceinline__ float sigf(float x){
  return __builtin_amdgcn_rcpf(1.f + __expf(-x));
}
__device__ __forceinline__ float tanhf_(float x){
  return 1.f - 2.f*__builtin_amdgcn_rcpf(1.f + __expf(2.f*x));
}
// LDS-only barrier, m201-verified pattern + rule #18 fences:
// sched_barrier(0) pins the machine scheduler on BOTH sides; lgkmcnt(0)
// completes this wave's LDS reads+writes; s_barrier syncs the block.
// vmem (enc stores / xg loads) stays in flight -- consumer-tracked.
__device__ __forceinline__ void barrier_lds(){
  __builtin_amdgcn_sched_barrier(0);
  asm volatile("s_waitcnt lgkmcnt(0)" ::: "memory");
  __builtin_amdgcn_s_barrier();
  __builtin_amdgcn_sched_barrier(0);
}

// ---------------- diagnostic --------------------------------------------------
__global__ void k_diag(float* out, float code){
  int i = blockIdx.x*256 + threadIdx.x;
  if(i<OUTN) out[i]=code;
}

// ---------------- fused probes ------------------------------------------------
__global__ void k_probes(const void* p, const int* __restrict__ words,
                         int* flag, int* iflag){
  __shared__ int cnt, zc;
  if(threadIdx.x==0){ cnt=0; zc=0; }
  __syncthreads();
  float a = fabsf(b2f(((const u16*)p)[threadIdx.x]));
  if(a>1e-5f && a<1.0f) atomicAdd(&cnt,1);
  if(threadIdx.x<64){
    int z=0;
    for(int k=threadIdx.x;k<128;k+=64)
      if(words[2*k+1]==0) z++;
    atomicAdd(&zc,z);
  }
  __syncthreads();
  if(threadIdx.x==0){ *flag=(cnt>=100)?1:0; *iflag=(zc>=100)?1:0; }
}

// ---------------- mega staging kernel (range-dispatched) ----------------------
__device__ __forceinline__ void st_wih(const void* src, u16* dst, int isb, int i){
  if(i>=NP*KP) return;
  int n=i/KP, k=i-n*KP;
  float v = (n<G4 && k<DIN) ? ldf(src,(long long)n*DIN+k,isb) : 0.f;
  dst[i]=f2b(v);
}
// w_hh -> MFMA B-frags, INTERLEAVED row order n' = j*4+gate (r16 layout)
__device__ __forceinline__ void st_whh(const void* src, u16* dst, int isb, int i){
  if(i>=179200) return;
  int tile=i/3584, r=i%3584, ks=r/512, r2=r%512, l=r2/8, jreg=r2%8;
  int c = tile*16 + (l&15);
  int j = c>>2, gate = c&3;
  int n = gate*200 + j;
  int k = ks*32 + ((l>>4)<<3) + jreg;
  float v = (k<HWg)? ldf(src,(long long)n*HWg+k,isb) : 0.f;
  dst[i]=f2b(v);
}
__global__ void k_stage(const void* wihf, const void* wihb,
                        const void* whhf, const void* whhb,
                        const void* echar, const void* convw, const void* cb,
                        const void* bfp, const void* bbp, const void* pw, const void* pb,
                        u16* dWIHF, u16* dWIHB, u16* dWHHF, u16* dWHHB,
                        float* d_ec, float* d_cw, float* d_cb,
                        float* d_bf, float* d_bb, float* d_pw, float* d_pb,
                        const int* __restrict__ flag){
  int isb=*flag;
  int bx=blockIdx.x, tid=threadIdx.x;
  if(bx<1232){ st_wih(wihf,dWIHF,isb,bx*256+tid); return; }
  bx-=1232;
  if(bx<1232){ st_wih(wihb,dWIHB,isb,bx*256+tid); return; }
  bx-=1232;
  if(bx<700){ st_whh(whhf,dWHHF,isb,bx*256+tid); return; }
  bx-=700;
  if(bx<700){ st_whh(whhb,dWHHB,isb,bx*256+tid); return; }
  bx-=700;
  int i = bx*256 + tid;
  if(i<2025){ d_ec[i]=ldf(echar,i,isb); return; } i-=2025;   // 81*25
  if(i<3750){ d_cw[i]=ldf(convw,i,isb); return; } i-=3750;   // 50*3*25
  if(i<64){ d_cb[i]=(i<50)?ldf(cb,i,isb):0.f; return; } i-=64;
  if(i<800){ d_bf[i]=ldf(bfp,i,isb); return; } i-=800;
  if(i<800){ d_bb[i]=ldf(bbp,i,isb); return; } i-=800;
  if(i<4000){ d_pw[i]=ldf(pw,i,isb); return; } i-=4000;
  if(i<16){ d_pb[i]=(i<10)?ldf(pb,i,isb):0.f; return; }
}

// ---------------- fused feats: word-emb gather + char CNN --------------------
__global__ __launch_bounds__(256) void k_feats(const void* __restrict__ words,
                      const void* __restrict__ chars, const void* __restrict__ embw,
                      const float* __restrict__ ec, const float* __restrict__ cw,
                      const float* __restrict__ cb, u16* __restrict__ feats,
                      const int* __restrict__ flag, const int* __restrict__ iflag){
  int isb=*flag, i64=*iflag;
  int bx=blockIdx.x, tid=threadIdx.x;
  if(bx<8192){
    int wv=tid>>6, lane=tid&63;
    int row = bx*4 + wv;
    int idx = ldi(words,row,i64);
    u16* d = feats + (size_t)row*KP;
    if(isb){
      const u16* s=(const u16*)embw + (long long)idx*DWg;
      for(int c=lane;c<DWg;c+=64) d[c]=s[c];
    } else {
      const float* s=(const float*)embw + (long long)idx*DWg;
      for(int c=lane;c<DWg;c+=64) d[c]=f2b(s[c]);
    }
    if(lane<2) d[350+lane]=0;
    return;
  }
  int gid = (bx-8192)*256 + tid;
  int w = gid/50, f = gid - w*50;
  int ch[20];
  #pragma unroll
  for(int r=0;r<20;r++) ch[r]=ldi(chars,(long long)w*LWW+r,i64);
  float acc[22];
  #pragma unroll
  for(int t=0;t<22;t++) acc[t]=0.f;
  for(int c=0;c<25;c++){
    float wv0=cw[(f*3+0)*25+c];
    float wv1=cw[(f*3+1)*25+c];
    float wv2=cw[(f*3+2)*25+c];
    #pragma unroll
    for(int r=0;r<20;r++){
      float xv = ec[ch[r]*25+c];
      acc[r+2] += xv*wv0;
      acc[r+1] += xv*wv1;
      acc[r]   += xv*wv2;
    }
  }
  float m=-1e30f;
  #pragma unroll
  for(int t=0;t<22;t++) m=fmaxf(m,acc[t]);
  feats[(size_t)w*KP + 300 + f] = f2b(m + cb[f]);
}

// ---------------- merged x-gate GEMM (both dirs, MFMA 128x128) ----------------
__global__ __launch_bounds__(256) void k_gemm(const u16* __restrict__ feats,
                      const u16* __restrict__ wihF, const float* __restrict__ biasF,
                      const u16* __restrict__ wihB, const float* __restrict__ biasB,
                      u16* __restrict__ xgF, u16* __restrict__ xgB){
  __shared__ u16 At[128*40];
  __shared__ u16 Bt[128*40];
  int tid=threadIdx.x, m0=blockIdx.x*128;
  int half = (blockIdx.y>=7);
  int n0 = (blockIdx.y - (half?7:0))*128;
  const u16* wih = half? wihB : wihF;
  const float* bias = half? biasB : biasF;
  u16* xg = half? xgB : xgF;
  int wv=tid>>6, lane=tid&63;
  int wr=(wv>>1)*64, wc=(wv&1)*64;
  const f32x4 z4={0.f,0.f,0.f,0.f};
  f32x4 acc[4][4];
  #pragma unroll
  for(int a=0;a<4;a++){ acc[a][0]=z4; acc[a][1]=z4; acc[a][2]=z4; acc[a][3]=z4; }
  int row=tid>>2, grp=tid&3;
  for(int kt=0;kt<11;kt++){
    int k0=kt*32;
    #pragma unroll
    for(int p=0;p<2;p++){
      int r=row+p*64;
      *(int4*)&At[r*40+grp*8] = *(const int4*)&feats[(size_t)(m0+r)*KP + k0 + grp*8];
      *(int4*)&Bt[r*40+grp*8] = *(const int4*)&wih  [(size_t)(n0+r)*KP + k0 + grp*8];
    }
    __syncthreads();
    bf16x8 af[4], bg[4];
    #pragma unroll
    for(int ri=0;ri<4;ri++) af[ri]=*(const bf16x8*)&At[(wr+ri*16+(lane&15))*40 + ((lane>>4)<<3)];
    #pragma unroll
    for(int ni=0;ni<4;ni++) bg[ni]=*(const bf16x8*)&Bt[(wc+ni*16+(lane&15))*40 + ((lane>>4)<<3)];
    #pragma unroll
    for(int ri=0;ri<4;ri++)
      #pragma unroll
      for(int ni=0;ni<4;ni++) acc[ri][ni]=mfma16(af[ri],bg[ni],acc[ri][ni]);
    __syncthreads();
  }
  #pragma unroll
  for(int ni=0;ni<4;ni++){
    int n = n0 + wc + ni*16 + (lane&15);
    if(n>=G4) continue;
    float bv = bias[n];
    int g4=n/200, j=n-g4*200;
    #pragma unroll
    for(int ri=0;ri<4;ri++)
      #pragma unroll
      for(int rr=0;rr<4;rr++){
        int m = m0 + wr + ri*16 + ((lane>>4)&3)*4 + rr;
        int b = m>>8, s = m&255;
        xg[((size_t)s*BB + b)*G4 + j*4 + g4] = f2b(acc[ri][ni][rr] + bv);
      }
  }
}

// ---------------- BiLSTM recurrence (r19 template, LDS-only in-loop barrier) --
__device__ __forceinline__ void lstm_upd(int lane, int t, int lenv,
    f32x4 a, u16x4 xrv, float& cstv, float& hregv,
    u16* __restrict__ enc, int eoffv, u16* hnp, int hboffv){
  float v0=a[0], v1=a[1], v2=a[2], v3=a[3];
  float f0,f1,r0,r1;
  const bool hi2=(lane&2)!=0;
  f0 = hi2? v0:v2; f1 = hi2? v1:v3;
  r0=__shfl_xor(f0,2); r1=__shfl_xor(f1,2);
  if(hi2){v0=r0;v1=r1;} else {v2=r0;v3=r1;}
  const bool hi1=(lane&1)!=0;
  f0 = hi1? v0:v1; f1 = hi1? v2:v3;
  r0=__shfl_xor(f0,1); r1=__shfl_xor(f1,1);
  if(hi1){v0=r0;v2=r1;} else {v1=r0;v3=r1;}
  float gi=v0+b2f(xrv.x), gf=v1+b2f(xrv.y);
  float gg=v2+b2f(xrv.z), go=v3+b2f(xrv.w);
  float iv=sigf(gi), fv=sigf(gf), gv=tanhf_(gg), ov=sigf(go);
  float cn=fv*cstv+iv*gv;
  float hv=ov*tanhf_(cn);
  const bool m = t<lenv;
  if(m){ cstv=cn; hregv=hv; }
  enc[(size_t)eoffv + (size_t)t*(2*HWg)] = m? f2b(hv):(u16)0;
  hnp[hboffv] = f2b(hregv);
}

__global__ __launch_bounds__(512,1) void k_lstm(
    const u16* __restrict__ xgf, const u16* __restrict__ xgb,
    const u16* __restrict__ whhf, const u16* __restrict__ whhb,
    const void* __restrict__ lens, u16* __restrict__ enc,
    const int* __restrict__ iflag)
{
  __shared__ u16 hbuf[2][16*232];
  __shared__ int len_s[16];
  __shared__ u16 wlds[7168];

  const int blk=blockIdx.x, dir=blk&1, b0=(blk>>1)*16;
  const u16* xg  = dir? xgb : xgf;
  const u16* whh = dir? whhb : whhf;
  const int tid=threadIdx.x, wv=tid>>6, lane=tid&63;
  const int i64=*iflag;

  for(int i=tid;i<2*16*232;i+=512) ((u16*)hbuf)[i]=0;
  if(tid<16) len_s[tid]=ldi(lens,b0+tid,i64);
  for(int i=tid;i<7168;i+=512) wlds[i]=whh[48*3584 + i];

  bf16x8 wf[6][7];
  #pragma unroll
  for(int i=0;i<6;i++)
    #pragma unroll
    for(int ks=0;ks<7;ks++)
      wf[i][ks]=*(const bf16x8*)&whh[(size_t)((wv*6+i)*7+ks)*512 + lane*8];

  const int bl = ((lane>>4)<<2) + (lane&3);       // 0..15
  const int jl = (lane>>2)&3;
  __syncthreads();
  const int lenv = len_s[bl];

  int xoff[7], eoff[7], hboff[7];
  #pragma unroll
  for(int q=0;q<6;q++){
    int j=(wv*6+q)*4+jl;
    xoff[q]=(b0+bl)*G4 + j*4;
    eoff[q]=((b0+bl)*SS)*(2*HWg) + dir*HWg + j;
    hboff[q]=bl*232 + j;
  }
  { int j=(48+wv)*4+jl;
    xoff[6]=(b0+bl)*G4 + j*4;
    eoff[6]=((b0+bl)*SS)*(2*HWg) + dir*HWg + j;
    hboff[6]=bl*232 + j; }

  float cst[7]={0,0,0,0,0,0,0}, hreg[7]={0,0,0,0,0,0,0};
  u16x4 xr[7];
  {
    const int t0 = dir? (SS-1):0;
    const size_t tb=(size_t)t0*(BB*G4);
    #pragma unroll
    for(int q=0;q<6;q++) xr[q]=*(const u16x4*)&xg[tb+xoff[q]];
    if(wv<2) xr[6]=*(const u16x4*)&xg[tb+xoff[6]];
  }

  const f32x4 z4={0.f,0.f,0.f,0.f};
  int cur=0;
  for(int step=0; step<SS; ++step){
    const int t = dir ? (SS-1-step) : step;
    int sn = step+1; if(sn>SS-1) sn=SS-1;
    const int tn = dir ? (SS-1-sn) : sn;
    const size_t tbn=(size_t)tn*(BB*G4);
    const u16* hc = hbuf[cur];
    u16* hn_ = hbuf[cur^1];

    bf16x8 afr[7];
    #pragma unroll
    for(int ks=0;ks<7;ks++)
      afr[ks]=*(const bf16x8*)&hc[(lane&15)*232 + ks*32 + ((lane>>4)<<3)];

    f32x4 acc[7];
    #pragma unroll
    for(int i=0;i<6;i++){
      acc[i]=z4;
      #pragma unroll
      for(int ks=0;ks<7;ks++) acc[i]=mfma16(afr[ks],wf[i][ks],acc[i]);
    }
    acc[6]=z4;
    if(wv<2){
      #pragma unroll
      for(int ks=0;ks<7;ks++){
        bf16x8 bw=*(const bf16x8*)&wlds[(wv*7+ks)*512 + lane*8];
        acc[6]=mfma16(afr[ks],bw,acc[6]);
      }
    }

    #pragma unroll
    for(int q=0;q<6;q++){
      lstm_upd(lane,t,lenv,acc[q],xr[q],cst[q],hreg[q],enc,eoff[q],hn_,hboff[q]);
      xr[q]=*(const u16x4*)&xg[tbn+xoff[q]];
    }
    if(wv<2){
      lstm_upd(lane,t,lenv,acc[6],xr[6],cst[6],hreg[6],enc,eoff[6],hn_,hboff[6]);
      xr[6]=*(const u16x4*)&xg[tbn+xoff[6]];
    }

    barrier_lds();       // LDS-only sync: enc stores / xg loads stay in flight
    cur^=1;
  }
}

// ---------------- emissions: one thread per (b,s) row, f32 output ------------
__global__ __launch_bounds__(256) void k_emis(const u16* __restrict__ enc,
                      const float* __restrict__ pw_g, const float* __restrict__ pb,
                      float* __restrict__ out){
  __shared__ float pw[10*404];
  __shared__ float pbs[16];
  int tid=threadIdx.x;
  for(int i=tid;i<4000;i+=256){ int tg=i/400,h=i-tg*400; pw[tg*404+h]=pw_g[i]; }
  if(tid<10) pbs[tid]=pb[tid];
  __syncthreads();
  int bs = blockIdx.x*256 + tid;                  // 32768 rows (128 blocks)
  const u16* er = enc + (size_t)bs*(2*HWg);
  float acc[10];
  #pragma unroll
  for(int tg=0;tg<10;tg++) acc[tg]=pbs[tg];
  for(int h=0;h<400;h+=4){
    u16x4 v=*(const u16x4*)&er[h];
    float e0=b2f(v.x), e1=b2f(v.y), e2=b2f(v.z), e3=b2f(v.w);
    #pragma unroll
    for(int tg=0;tg<10;tg++)
      acc[tg] += e0*pw[tg*404+h]   + e1*pw[tg*404+h+1]
               + e2*pw[tg*404+h+2] + e3*pw[tg*404+h+3];
  }
  float* o = out + (size_t)bs*10;
  #pragma unroll
  for(int tg=0;tg<10;tg++) o[tg]=acc[tg];
}

// ---------------- launch -----------------------------------------------------
extern "C" void kernel_launch(void* const* d_in, const int* in_sizes, int n_in,
                              void* d_out, int out_size, void* d_ws, size_t ws_size,
                              hipStream_t stream){
  float* out=(float*)d_out;
  if(n_in!=15){ k_diag<<<1280,256,0,stream>>>(out, 20480.f); return; }
  if(out_size!=OUTN){ k_diag<<<1280,256,0,stream>>>(out, 24576.f); return; }

  const void* words=d_in[0];
  const void* chars=d_in[1];
  const void* lens =d_in[2];
  const void* echar=d_in[3];
  const void* embw =d_in[4];
  const void* convw=d_in[5];
  const void* convb=d_in[6];
  const void* wihf =d_in[7];
  const void* whhf =d_in[8];
  const void* bfp  =d_in[9];
  const void* wihb =d_in[10];
  const void* whhb =d_in[11];
  const void* bbp  =d_in[12];
  const void* pw   =d_in[13];
  const void* pb   =d_in[14];

  char* ws=(char*)d_ws;
  size_t cur=0;
  auto alloc=[&](size_t sz){ size_t o=cur; cur=(cur+sz+255)&~(size_t)255; return o; };
  size_t oF    = alloc(4);
  size_t oIF   = alloc(4);
  size_t oWIHF = alloc((size_t)NP*KP*2);
  size_t oWIHB = alloc((size_t)NP*KP*2);
  size_t oWHHF = alloc(179200*2);
  size_t oWHHB = alloc(179200*2);
  size_t oEC   = alloc(2025*4);
  size_t oCW   = alloc(3750*4);
  size_t oCB   = alloc(64*4);
  size_t oBF   = alloc(800*4);
  size_t oBB   = alloc(800*4);
  size_t oPW   = alloc(4000*4);
  size_t oPB   = alloc(16*4);
  size_t oSH   = alloc((size_t)NW*2*HWg*2);       // feats / enc alias (bf16)
  size_t oXGF  = alloc((size_t)SS*BB*G4*2);
  size_t oXGB  = alloc((size_t)SS*BB*G4*2);
  size_t need  = cur;

  if(ws_size < need){
    k_diag<<<1280,256,0,stream>>>(out, 16384.f + 64.f*(float)(ws_size>>20));
    return;
  }

  int*   flag =(int*)(ws+oF);
  int*   iflag=(int*)(ws+oIF);
  u16*   sWIHF=(u16*)(ws+oWIHF);
  u16*   sWIHB=(u16*)(ws+oWIHB);
  u16*   sWHHF=(u16*)(ws+oWHHF);
  u16*   sWHHB=(u16*)(ws+oWHHB);
  float* sEC  =(float*)(ws+oEC);
  float* sCW  =(float*)(ws+oCW);
  float* sCB  =(float*)(ws+oCB);
  float* sBF  =(float*)(ws+oBF);
  float* sBB  =(float*)(ws+oBB);
  float* sPW  =(float*)(ws+oPW);
  float* sPB  =(float*)(ws+oPB);
  u16*   feats=(u16*)(ws+oSH);
  u16*   enc  =(u16*)(ws+oSH);                    // alias (feats dead post-GEMM)
  u16*   xgfp =(u16*)(ws+oXGF);
  u16*   xgbp =(u16*)(ws+oXGB);

  k_probes<<<1,128,0,stream>>>(embw, (const int*)words, flag, iflag);
  k_stage<<<3909,256,0,stream>>>(wihf, wihb, whhf, whhb,
                                 echar, convw, convb, bfp, bbp, pw, pb,
                                 sWIHF, sWIHB, sWHHF, sWHHB,
                                 sEC, sCW, sCB, sBF, sBB, sPW, sPB, flag);
  k_feats<<<14592,256,0,stream>>>(words, chars, embw, sEC, sCW, sCB,
                                  feats, flag, iflag);
  k_gemm<<<dim3(256,14),256,0,stream>>>(feats, sWIHF, sBF, sWIHB, sBB, xgfp, xgbp);
  k_lstm<<<16,512,0,stream>>>(xgfp, xgbp, sWHHF, sWHHB, lens, enc, iflag);
  k_emis<<<128,256,0,stream>>>(enc, sPW, sPB, out);
}